// Round 5
// baseline (151.635 us; speedup 1.0000x reference)
//
#include <hip/hip_runtime.h>
#include <hip/hip_bf16.h>
#include <stdint.h>
#include <stddef.h>

#define T_S 4096
#define D_M 1024
#define NH_ 16
#define EPSF 1.1920929e-07f

typedef float f32x4 __attribute__((ext_vector_type(4)));
typedef __bf16 bf16x8 __attribute__((ext_vector_type(8)));
typedef short short8 __attribute__((ext_vector_type(8)));
typedef unsigned short ushort4v __attribute__((ext_vector_type(4)));

static __device__ __forceinline__ unsigned short f2bf(float f) {
  unsigned int u = __builtin_bit_cast(unsigned int, f);
  unsigned int r = (u + 0x7fffu + ((u >> 16) & 1u)) >> 16;
  return (unsigned short)r;
}

#define GLDS16(gp, lp) __builtin_amdgcn_global_load_lds( \
    (__attribute__((address_space(1))) void*)(gp),       \
    (__attribute__((address_space(3))) void*)(lp), 16, 0, 0)

static __device__ __forceinline__ f32x4 mfma16(bf16x8 a, bf16x8 b, f32x4 c) {
  return __builtin_amdgcn_mfma_f32_16x16x32_bf16(a, b, c, 0, 0, 0);
}

// ---------------- RoPE cos/sin table: [T][32] ----------------
__global__ __launch_bounds__(256) void k_rope_tab(float* __restrict__ cosT,
                                                  float* __restrict__ sinT) {
  int i = blockIdx.x * 256 + threadIdx.x;  // t*32 + f
  int t = i >> 5, f = i & 31;
  float fr = (f < 16) ? powf(1e-4f, (float)f * (1.0f / 15.0f)) : 0.0f;
  float th = (float)t * fr;
  cosT[i] = cosf(th);
  sinT[i] = sinf(th);
}

// ---------------- f32 -> bf16 ----------------
__global__ __launch_bounds__(256) void k_f32_to_bf16(const float* __restrict__ src,
                                                     unsigned short* __restrict__ dst) {
  int i = blockIdx.x * 256 + threadIdx.x;
  float4 v = ((const float4*)src)[i];
  ushort4v o;
  o.x = f2bf(v.x); o.y = f2bf(v.y); o.z = f2bf(v.z); o.w = f2bf(v.w);
  ((ushort4v*)dst)[i] = o;
}

// ---------------- RMSNorm over D=1024 + cast ----------------
__global__ __launch_bounds__(256) void k_rmsnorm_cast(const float* __restrict__ x,
                                                      unsigned short* __restrict__ xn) {
  const int row = blockIdx.x;
  const int tid = threadIdx.x;
  float4 v = ((const float4*)(x + (size_t)row * D_M))[tid];
  float ss = v.x * v.x + v.y * v.y + v.z * v.z + v.w * v.w;
#pragma unroll
  for (int d = 1; d < 64; d <<= 1) ss += __shfl_xor(ss, d, 64);
  __shared__ float red[4];
  if ((tid & 63) == 0) red[tid >> 6] = ss;
  __syncthreads();
  float sc = rsqrtf((red[0] + red[1] + red[2] + red[3]) * (1.0f / D_M) + EPSF);
  ushort4v o;
  o.x = f2bf(v.x * sc); o.y = f2bf(v.y * sc); o.z = f2bf(v.z * sc); o.w = f2bf(v.w * sc);
  ((ushort4v*)(xn + (size_t)row * D_M))[tid] = o;
}

// ---------------- bf16 GEMM, C = A @ B^T, 2-phase/K-tile deep pipeline ----------------
// BM=128, BN=256, BK=64, K=1024 (NT=16). 8 waves (2M x 4N), wave tile 64x64.
// LDS per buffer (48KB): Akh0@0(8K), Akh1@8K, Bkh0@16K(16K), Bkh1@32K. 2 buffers.
// Phase p0 reads kh0 (8 ds_read_b128, 16 MFMA); p1 reads kh1.
// Staging (3 gloads per half = A 1 + B 2):
//   p0 issues kh1(T+1) -> clobbers kh1(T-1), last read T-1.p1, ordered by W_T barrier.
//   p1 issues kh0(T+2) -> clobbers kh0(T), last read T.p0, ordered by end-p0 barrier.
// W_{T+1} wait: vmcnt(3) if kh0(T+2) was issued else vmcnt(0). Rows are 64B
// (kh-split) so (r&1,g4) covers all 32 banks: conflict-free, linear staging.
// EPI 0: fused per-head RMSNorm+RoPE scatter -> q/k/v head-major bf16 [n,h,t,d]
// EPI 1: Cf = resid + scale[col]*acc (f32)
template <int EPI>
__global__ __launch_bounds__(512, 2) void k_gemm2p(
    const unsigned short* __restrict__ A, const unsigned short* __restrict__ B,
    unsigned short* __restrict__ q_out, unsigned short* __restrict__ k_out,
    unsigned short* __restrict__ v_out, float* __restrict__ Cf,
    const float* __restrict__ resid, const float* __restrict__ scale,
    const float* __restrict__ cosT, const float* __restrict__ sinT,
    int cpx) {
  extern __shared__ __align__(16) char lds[];  // 2 x 49152
  const int tid = threadIdx.x;
  const int lane = tid & 63, w = tid >> 6;
  const int lrow = lane & 15, g4 = lane >> 4;
  const int wm = w >> 2, wn = w & 3;
  const int id = (blockIdx.x & 7) * cpx + (blockIdx.x >> 3);
  const int m0 = (id & 63) * 128, n0 = (id >> 6) * 256;

  auto stA = [&](int t, int kh, int dbx) {
    const unsigned short* s =
        A + (size_t)(m0 + (tid >> 2)) * 1024 + t * 64 + kh * 32 + ((tid & 3) << 3);
    GLDS16(s, lds + dbx * 49152 + kh * 8192 + tid * 16);
  };
  auto stB = [&](int t, int kh, int dbx) {
#pragma unroll
    for (int it = 0; it < 2; ++it) {
      int ci = it * 512 + tid;
      const unsigned short* s =
          B + (size_t)(n0 + (ci >> 2)) * 1024 + t * 64 + kh * 32 + ((ci & 3) << 3);
      GLDS16(s, lds + dbx * 49152 + 16384 + kh * 16384 + ci * 16);
    }
  };

  int a_off[2][4], b_off[2][4];
#pragma unroll
  for (int kh = 0; kh < 2; ++kh) {
#pragma unroll
    for (int i = 0; i < 4; ++i) {
      a_off[kh][i] = kh * 8192 + (wm * 64 + i * 16 + lrow) * 64 + g4 * 16;
      b_off[kh][i] = 16384 + kh * 16384 + (wn * 64 + i * 16 + lrow) * 64 + g4 * 16;
    }
  }

  f32x4 acc[4][4] = {};

  // prologue: kh0(0), kh1(0), kh0(1)
  stA(0, 0, 0); stB(0, 0, 0);
  stA(0, 1, 0); stB(0, 1, 0);
  stA(1, 0, 1); stB(1, 0, 1);
  asm volatile("s_waitcnt vmcnt(3)" ::: "memory");
  __builtin_amdgcn_s_barrier();
  asm volatile("" ::: "memory");

  for (int T = 0; T < 16; ++T) {
    const int db = T & 1;
    const char* cp = lds + db * 49152;
    // ---- phase 0 (kh0) ----
    {
      bf16x8 aF[4], bF[4];
#pragma unroll
      for (int i = 0; i < 4; ++i) aF[i] = *(const bf16x8*)(cp + a_off[0][i]);
#pragma unroll
      for (int i = 0; i < 4; ++i) bF[i] = *(const bf16x8*)(cp + b_off[0][i]);
      if (T < 15) { stA(T + 1, 1, db ^ 1); stB(T + 1, 1, db ^ 1); }
      __builtin_amdgcn_s_setprio(1);
#pragma unroll
      for (int mi = 0; mi < 4; ++mi)
#pragma unroll
        for (int ni = 0; ni < 4; ++ni)
          acc[mi][ni] = mfma16(aF[mi], bF[ni], acc[mi][ni]);
      __builtin_amdgcn_s_setprio(0);
      asm volatile("" ::: "memory");
      __builtin_amdgcn_s_barrier();
      asm volatile("" ::: "memory");
    }
    // ---- phase 1 (kh1) ----
    {
      bf16x8 aF[4], bF[4];
#pragma unroll
      for (int i = 0; i < 4; ++i) aF[i] = *(const bf16x8*)(cp + a_off[1][i]);
#pragma unroll
      for (int i = 0; i < 4; ++i) bF[i] = *(const bf16x8*)(cp + b_off[1][i]);
      if (T < 14) { stA(T + 2, 0, db); stB(T + 2, 0, db); }
      __builtin_amdgcn_s_setprio(1);
#pragma unroll
      for (int mi = 0; mi < 4; ++mi)
#pragma unroll
        for (int ni = 0; ni < 4; ++ni)
          acc[mi][ni] = mfma16(aF[mi], bF[ni], acc[mi][ni]);
      __builtin_amdgcn_s_setprio(0);
      if (T < 14)
        asm volatile("s_waitcnt vmcnt(3)" ::: "memory");
      else
        asm volatile("s_waitcnt vmcnt(0)" ::: "memory");
      __builtin_amdgcn_s_barrier();
      asm volatile("" ::: "memory");
    }
  }

  const int rbase = m0 + wm * 64 + g4 * 4;  // + mi*16 + j
  const int colbase = n0 + wn * 64;         // wave covers exactly one head

  if (EPI == 1) {
#pragma unroll
    for (int mi = 0; mi < 4; ++mi)
#pragma unroll
      for (int nf = 0; nf < 4; ++nf) {
        int col = colbase + nf * 16 + lrow;
        float sc = scale[col];
#pragma unroll
        for (int j = 0; j < 4; ++j) {
          int row = rbase + mi * 16 + j;
          size_t idx = (size_t)row * 1024 + col;
          Cf[idx] = resid[idx] + sc * acc[mi][nf][j];
        }
      }
  } else {
    const int which = colbase >> 10;
    const int hh = (colbase >> 6) & 15;
    if (which == 2) {
#pragma unroll
      for (int mi = 0; mi < 4; ++mi)
#pragma unroll
        for (int j = 0; j < 4; ++j) {
          int row = rbase + mi * 16 + j;
          int t = row & (T_S - 1), nn = row >> 12;
          size_t ob = ((size_t)(nn * NH_ + hh) * T_S + t) * 64;
#pragma unroll
          for (int nf = 0; nf < 4; ++nf)
            v_out[ob + nf * 16 + lrow] = f2bf(acc[mi][nf][j]);
        }
    } else {
      unsigned short* dst = which ? k_out : q_out;
#pragma unroll
      for (int mi = 0; mi < 4; ++mi)
#pragma unroll
        for (int j = 0; j < 4; ++j) {
          int row = rbase + mi * 16 + j;
          int t = row & (T_S - 1), nn = row >> 12;
          float ss = 0.0f;
#pragma unroll
          for (int nf = 0; nf < 4; ++nf) ss += acc[mi][nf][j] * acc[mi][nf][j];
          ss += __shfl_xor(ss, 1, 64);
          ss += __shfl_xor(ss, 2, 64);
          ss += __shfl_xor(ss, 4, 64);
          ss += __shfl_xor(ss, 8, 64);
          float sc = rsqrtf(ss * (1.0f / 64.0f) + EPSF);
          size_t ob = ((size_t)(nn * NH_ + hh) * T_S + t) * 64;
#pragma unroll
          for (int nf = 0; nf < 2; ++nf) {
            int dd = nf * 16 + lrow;
            float cs = cosT[t * 32 + dd], sn = sinT[t * 32 + dd];
            float z1 = acc[mi][nf][j] * sc, z2 = acc[mi][nf + 2][j] * sc;
            dst[ob + dd] = f2bf(z1 * cs + z2 * sn);
            dst[ob + dd + 32] = f2bf(z2 * cs - z1 * sn);
          }
        }
    }
  }
}

// ---------------- chunked sliding-window attention (windowed) ----------------
__global__ __launch_bounds__(256) void k_attn(const unsigned short* __restrict__ qh,
                                              const unsigned short* __restrict__ kh,
                                              const unsigned short* __restrict__ vh,
                                              unsigned short* __restrict__ ao) {
  extern __shared__ __align__(16) char lds[];
  unsigned short* Vt = (unsigned short*)lds;                    // [64][264]
  unsigned short* Pb = (unsigned short*)(lds + 64 * 264 * 2);   // 4 x [32][72]
  const int b = blockIdx.x;
  const int c = b & 31, nh = b >> 5;
  const int tid = threadIdx.x, lane = tid & 63, w = tid >> 6;
  const int lrow = lane & 15, g = lane >> 4, lk8 = g * 8;
  const size_t hb = (size_t)nh * T_S * 64;
  const unsigned short* qg = qh + hb + (size_t)c * 128 * 64;
  const unsigned short* kg = kh + hb + ((ptrdiff_t)c * 128 - 128) * 64;
  const unsigned short* vg = vh + hb + ((ptrdiff_t)c * 128 - 128) * 64;

  // stage V transposed via register 8x8 transpose, b128 writes
  {
    const int m_idx = (tid & 7) | ((tid >> 6) << 3);
    const int m0v = m_idx * 8;
    const int d0 = ((tid >> 3) & 7) * 8;
    short8 vv[8];
#pragma unroll
    for (int i = 0; i < 8; ++i) {
      short8 z = {0, 0, 0, 0, 0, 0, 0, 0};
      if (!(c == 0 && m0v < 128)) z = *(const short8*)(vg + (size_t)(m0v + i) * 64 + d0);
      vv[i] = z;
    }
#pragma unroll
    for (int jj = 0; jj < 8; ++jj) {
      short8 wv;
#pragma unroll
      for (int i = 0; i < 8; ++i) wv[i] = vv[i][jj];
      *(short8*)(Vt + (size_t)(d0 + jj) * 264 + m0v) = wv;
    }
  }

  // Q fragments
  bf16x8 qf[2][2];
#pragma unroll
  for (int mi = 0; mi < 2; ++mi)
#pragma unroll
    for (int ks = 0; ks < 2; ++ks)
      qf[mi][ks] =
          *(const bf16x8*)(qg + (size_t)(w * 32 + mi * 16 + lrow) * 64 + ks * 32 + lk8);

  // S = Q K^T over the wave's 10-tile window
  const int nlo = 2 * w;
  f32x4 s[2][10] = {};
#pragma unroll
  for (int u = 0; u < 10; ++u) {
    const int ni = nlo + u;
    if (c == 0 && ni < 8) continue;
    bf16x8 kf0 = *(const bf16x8*)(kg + (size_t)(ni * 16 + lrow) * 64 + lk8);
    bf16x8 kf1 = *(const bf16x8*)(kg + (size_t)(ni * 16 + lrow) * 64 + 32 + lk8);
#pragma unroll
    for (int mi = 0; mi < 2; ++mi) {
      s[mi][u] = mfma16(qf[mi][0], kf0, s[mi][u]);
      s[mi][u] = mfma16(qf[mi][1], kf1, s[mi][u]);
    }
  }

  // mask + scale + row softmax (deferred normalization)
  float invs[2][4];
#pragma unroll
  for (int mi = 0; mi < 2; ++mi) {
#pragma unroll
    for (int j = 0; j < 4; ++j) {
      int jq = w * 32 + mi * 16 + g * 4 + j;
      float mx = -1e30f;
#pragma unroll
      for (int u = 0; u < 10; ++u) {
        int m = (nlo + u) * 16 + lrow;
        bool ok = (m > jq) && (m <= 128 + jq) && (c > 0 || m >= 128);
        float val = ok ? s[mi][u][j] * 0.125f : -1e30f;
        s[mi][u][j] = val;
        mx = fmaxf(mx, val);
      }
#pragma unroll
      for (int d2 = 1; d2 < 16; d2 <<= 1) mx = fmaxf(mx, __shfl_xor(mx, d2, 64));
      float sum = 0.0f;
#pragma unroll
      for (int u = 0; u < 10; ++u) {
        float p = __expf(s[mi][u][j] - mx);
        s[mi][u][j] = p;
        sum += p;
      }
#pragma unroll
      for (int d2 = 1; d2 < 16; d2 <<= 1) sum += __shfl_xor(sum, d2, 64);
      invs[mi][j] = 1.0f / sum;
    }
  }

  __syncthreads();  // Vt staged before PV reads

  // PV over 3 quarters; P staged per-wave in LDS (stride 72), unnormalized
  f32x4 oacc[2][4] = {};
  unsigned short* Pw = Pb + w * (32 * 72);
  const int qlo = w >> 1;
#pragma unroll
  for (int qq = 0; qq < 3; ++qq) {
#pragma unroll
    for (int mi = 0; mi < 2; ++mi)
#pragma unroll
      for (int ni4 = 0; ni4 < 4; ++ni4)
#pragma unroll
        for (int j = 0; j < 4; ++j) {
          int r = mi * 16 + g * 4 + j;
          float val;
          if ((w & 1) == 0) {
            int u = qq * 4 + ni4;
            val = (u < 10) ? s[mi][u < 10 ? u : 0][j] : 0.0f;
          } else {
            int u = qq * 4 + ni4 - 2;
            val = (u >= 0 && u < 10) ? s[mi][(u >= 0 && u < 10) ? u : 0][j] : 0.0f;
          }
          Pw[r * 72 + ni4 * 16 + lrow] = f2bf(val);
        }
    const int qi = qlo + qq;
#pragma unroll
    for (int ks = 0; ks < 2; ++ks) {
      bf16x8 pf[2], vf[4];
#pragma unroll
      for (int mi = 0; mi < 2; ++mi)
        pf[mi] = *(const bf16x8*)&Pw[(mi * 16 + lrow) * 72 + ks * 32 + lk8];
#pragma unroll
      for (int nj = 0; nj < 4; ++nj)
        vf[nj] = *(const bf16x8*)&Vt[(nj * 16 + lrow) * 264 + qi * 64 + ks * 32 + lk8];
#pragma unroll
      for (int mi = 0; mi < 2; ++mi)
#pragma unroll
        for (int nj = 0; nj < 4; ++nj)
          oacc[mi][nj] = mfma16(pf[mi], vf[nj], oacc[mi][nj]);
    }
  }

  const int t0 = c * 128 + w * 32;
  const int n_ = nh >> 4, h_ = nh & 15;
#pragma unroll
  for (int mi = 0; mi < 2; ++mi)
#pragma unroll
    for (int nj = 0; nj < 4; ++nj)
#pragma unroll
      for (int j = 0; j < 4; ++j) {
        int t = t0 + mi * 16 + g * 4 + j;
        int dcol = nj * 16 + lrow;
        ao[((size_t)n_ * T_S + t) * D_M + h_ * 64 + dcol] =
            f2bf(oacc[mi][nj][j] * invs[mi][j]);
      }
}

extern "C" void kernel_launch(void* const* d_in, const int* in_sizes, int n_in,
                              void* d_out, int out_size, void* d_ws, size_t ws_size,
                              hipStream_t stream) {
  const float* x = (const float*)d_in[0];      // [2,4096,1024]
  const float* qkvw = (const float*)d_in[1];   // [3,1024,1024]
  const float* ow = (const float*)d_in[2];     // [1024,1024]
  const float* osc = (const float*)d_in[3];    // [1024]
  float* out = (float*)d_out;

  char* ws = (char*)d_ws;
  unsigned short* xn = (unsigned short*)(ws + 0);
  unsigned short* qkvwb = (unsigned short*)(ws + 16777216);
  unsigned short* owb = (unsigned short*)(ws + 23068672);
  unsigned short* qhb = (unsigned short*)(ws + 25165824);
  unsigned short* khb = (unsigned short*)(ws + 41943040);
  unsigned short* vhb = (unsigned short*)(ws + 58720256);
  unsigned short* aob = (unsigned short*)(ws + 75497472);
  float* cosT = (float*)(ws + 92274688);
  float* sinT = (float*)(ws + 92798976);

  k_rope_tab<<<512, 256, 0, stream>>>(cosT, sinT);
  k_f32_to_bf16<<<3072, 256, 0, stream>>>(qkvw, qkvwb);
  k_f32_to_bf16<<<1024, 256, 0, stream>>>(ow, owb);
  k_rmsnorm_cast<<<8192, 256, 0, stream>>>(x, xn);
  // QKV: grid 64(M) x 12(N) = 768 blocks = 3 exact rounds, XCD-swizzled
  k_gemm2p<0><<<768, 512, 98304, stream>>>(xn, qkvwb, qhb, khb, vhb, nullptr,
                                           nullptr, nullptr, cosT, sinT, 96);
  k_attn<<<1024, 256, 52224, stream>>>(qhb, khb, vhb, aob);
  // O-proj: grid 64(M) x 4(N) = 256 blocks = 1 exact round
  k_gemm2p<1><<<256, 512, 98304, stream>>>(aob, owb, nullptr, nullptr, nullptr, out,
                                           x, osc, nullptr, nullptr, 32);
}

// Round 6
// 151.057 us; speedup vs baseline: 1.0038x; 1.0038x over previous
//
#include <hip/hip_runtime.h>
#include <hip/hip_bf16.h>
#include <stdint.h>
#include <stddef.h>

#define T_S 4096
#define D_M 1024
#define NH_ 16
#define EPSF 1.1920929e-07f

typedef float f32x4 __attribute__((ext_vector_type(4)));
typedef __bf16 bf16x8 __attribute__((ext_vector_type(8)));
typedef short short8 __attribute__((ext_vector_type(8)));
typedef unsigned short ushort4v __attribute__((ext_vector_type(4)));

static __device__ __forceinline__ unsigned short f2bf(float f) {
  unsigned int u = __builtin_bit_cast(unsigned int, f);
  unsigned int r = (u + 0x7fffu + ((u >> 16) & 1u)) >> 16;
  return (unsigned short)r;
}

#define GLDS16(gp, lp) __builtin_amdgcn_global_load_lds( \
    (__attribute__((address_space(1))) void*)(gp),       \
    (__attribute__((address_space(3))) void*)(lp), 16, 0, 0)

static __device__ __forceinline__ f32x4 mfma16(bf16x8 a, bf16x8 b, f32x4 c) {
  return __builtin_amdgcn_mfma_f32_16x16x32_bf16(a, b, c, 0, 0, 0);
}

// ---------------- RoPE cos/sin table: [T][32] ----------------
__global__ __launch_bounds__(256) void k_rope_tab(float* __restrict__ cosT,
                                                  float* __restrict__ sinT) {
  int i = blockIdx.x * 256 + threadIdx.x;  // t*32 + f
  int t = i >> 5, f = i & 31;
  float fr = (f < 16) ? powf(1e-4f, (float)f * (1.0f / 15.0f)) : 0.0f;
  float th = (float)t * fr;
  cosT[i] = cosf(th);
  sinT[i] = sinf(th);
}

// ---------------- f32 -> bf16 ----------------
__global__ __launch_bounds__(256) void k_f32_to_bf16(const float* __restrict__ src,
                                                     unsigned short* __restrict__ dst) {
  int i = blockIdx.x * 256 + threadIdx.x;
  float4 v = ((const float4*)src)[i];
  ushort4v o;
  o.x = f2bf(v.x); o.y = f2bf(v.y); o.z = f2bf(v.z); o.w = f2bf(v.w);
  ((ushort4v*)dst)[i] = o;
}

// ---------------- RMSNorm over D=1024 + cast ----------------
__global__ __launch_bounds__(256) void k_rmsnorm_cast(const float* __restrict__ x,
                                                      unsigned short* __restrict__ xn) {
  const int row = blockIdx.x;
  const int tid = threadIdx.x;
  float4 v = ((const float4*)(x + (size_t)row * D_M))[tid];
  float ss = v.x * v.x + v.y * v.y + v.z * v.z + v.w * v.w;
#pragma unroll
  for (int d = 1; d < 64; d <<= 1) ss += __shfl_xor(ss, d, 64);
  __shared__ float red[4];
  if ((tid & 63) == 0) red[tid >> 6] = ss;
  __syncthreads();
  float sc = rsqrtf((red[0] + red[1] + red[2] + red[3]) * (1.0f / D_M) + EPSF);
  ushort4v o;
  o.x = f2bf(v.x * sc); o.y = f2bf(v.y * sc); o.z = f2bf(v.z * sc); o.w = f2bf(v.w * sc);
  ((ushort4v*)(xn + (size_t)row * D_M))[tid] = o;
}

// ---------------- bf16 GEMM, C = A @ B^T, 2-phase/K-tile deep pipeline ----------------
// BM=128, BN=256, BK=64, K=1024 (NT=16). 8 waves (2M x 4N), wave tile 64x64.
// LDS per buffer (48KB): Akh0@0(8K), Akh1@8K, Bkh0@16K(16K), Bkh1@32K. 2 buffers.
// Staging ledger:
//   p0 issues kh1(T+1) -> clobbers kh1(T-1), last read T-1.p1, ordered by W_T barrier.
//   p1 issues kh0(T+2) -> clobbers kh0(T), last read T.p0, ordered by end-p0 barrier.
//   W_{T+1} wait: vmcnt(3) if kh0(T+2) issued, else vmcnt(0).
// LDS XOR swizzle (both sides, R2-proven 0-conflict): 16B group in row r lives at
// slot g ^ ((r>>1)&3); staging source pre-applies the same involution.
// EPI 0: fused per-head RMSNorm+RoPE scatter -> q/k/v head-major bf16 [n,h,t,d]
// EPI 1: Cf = resid + scale[col]*acc (f32)
template <int EPI>
__global__ __launch_bounds__(512, 2) void k_gemm2p(
    const unsigned short* __restrict__ A, const unsigned short* __restrict__ B,
    unsigned short* __restrict__ q_out, unsigned short* __restrict__ k_out,
    unsigned short* __restrict__ v_out, float* __restrict__ Cf,
    const float* __restrict__ resid, const float* __restrict__ scale,
    const float* __restrict__ cosT, const float* __restrict__ sinT,
    int cpx) {
  extern __shared__ __align__(16) char lds[];  // 2 x 49152
  const int tid = threadIdx.x;
  const int lane = tid & 63, w = tid >> 6;
  const int lrow = lane & 15, g4 = lane >> 4;
  const int wm = w >> 2, wn = w & 3;
  const int id = (blockIdx.x & 7) * cpx + (blockIdx.x >> 3);
  const int m0 = (id & 63) * 128, n0 = (id >> 6) * 256;

  auto stA = [&](int t, int kh, int dbx) {
    // linear LDS dest tid*16 = row (tid>>2), slot (tid&3); source group = slot ^ ((row>>1)&3)
    const int sg = ((tid & 3) ^ ((tid >> 3) & 3)) << 3;
    const unsigned short* s =
        A + (size_t)(m0 + (tid >> 2)) * 1024 + t * 64 + kh * 32 + sg;
    GLDS16(s, lds + dbx * 49152 + kh * 8192 + tid * 16);
  };
  auto stB = [&](int t, int kh, int dbx) {
#pragma unroll
    for (int it = 0; it < 2; ++it) {
      int ci = it * 512 + tid;
      const int sg = ((ci & 3) ^ ((ci >> 3) & 3)) << 3;
      const unsigned short* s =
          B + (size_t)(n0 + (ci >> 2)) * 1024 + t * 64 + kh * 32 + sg;
      GLDS16(s, lds + dbx * 49152 + 16384 + kh * 16384 + ci * 16);
    }
  };

  int a_off[2][4], b_off[2][4];
#pragma unroll
  for (int kh = 0; kh < 2; ++kh) {
#pragma unroll
    for (int i = 0; i < 4; ++i) {
      int ar = wm * 64 + i * 16 + lrow;
      a_off[kh][i] = kh * 8192 + ar * 64 + ((g4 ^ ((ar >> 1) & 3)) << 4);
      int br = wn * 64 + i * 16 + lrow;
      b_off[kh][i] = 16384 + kh * 16384 + br * 64 + ((g4 ^ ((br >> 1) & 3)) << 4);
    }
  }

  f32x4 acc[4][4] = {};

  // prologue: kh0(0), kh1(0), kh0(1)
  stA(0, 0, 0); stB(0, 0, 0);
  stA(0, 1, 0); stB(0, 1, 0);
  stA(1, 0, 1); stB(1, 0, 1);
  asm volatile("s_waitcnt vmcnt(3)" ::: "memory");
  __builtin_amdgcn_s_barrier();
  asm volatile("" ::: "memory");

  for (int T = 0; T < 16; ++T) {
    const int db = T & 1;
    const char* cp = lds + db * 49152;
    // ---- phase 0 (kh0) ----
    {
      bf16x8 aF[4], bF[4];
#pragma unroll
      for (int i = 0; i < 4; ++i) aF[i] = *(const bf16x8*)(cp + a_off[0][i]);
#pragma unroll
      for (int i = 0; i < 4; ++i) bF[i] = *(const bf16x8*)(cp + b_off[0][i]);
      if (T < 15) { stA(T + 1, 1, db ^ 1); stB(T + 1, 1, db ^ 1); }
      __builtin_amdgcn_s_setprio(1);
#pragma unroll
      for (int mi = 0; mi < 4; ++mi)
#pragma unroll
        for (int ni = 0; ni < 4; ++ni)
          acc[mi][ni] = mfma16(aF[mi], bF[ni], acc[mi][ni]);
      __builtin_amdgcn_s_setprio(0);
      asm volatile("" ::: "memory");
      __builtin_amdgcn_s_barrier();
      asm volatile("" ::: "memory");
    }
    // ---- phase 1 (kh1) ----
    {
      bf16x8 aF[4], bF[4];
#pragma unroll
      for (int i = 0; i < 4; ++i) aF[i] = *(const bf16x8*)(cp + a_off[1][i]);
#pragma unroll
      for (int i = 0; i < 4; ++i) bF[i] = *(const bf16x8*)(cp + b_off[1][i]);
      if (T < 14) { stA(T + 2, 0, db); stB(T + 2, 0, db); }
      __builtin_amdgcn_s_setprio(1);
#pragma unroll
      for (int mi = 0; mi < 4; ++mi)
#pragma unroll
        for (int ni = 0; ni < 4; ++ni)
          acc[mi][ni] = mfma16(aF[mi], bF[ni], acc[mi][ni]);
      __builtin_amdgcn_s_setprio(0);
      if (T < 14)
        asm volatile("s_waitcnt vmcnt(3)" ::: "memory");
      else
        asm volatile("s_waitcnt vmcnt(0)" ::: "memory");
      __builtin_amdgcn_s_barrier();
      asm volatile("" ::: "memory");
    }
  }

  const int rbase = m0 + wm * 64 + g4 * 4;  // + mi*16 + j
  const int colbase = n0 + wn * 64;         // wave covers exactly one head

  if (EPI == 1) {
#pragma unroll
    for (int mi = 0; mi < 4; ++mi)
#pragma unroll
      for (int nf = 0; nf < 4; ++nf) {
        int col = colbase + nf * 16 + lrow;
        float sc = scale[col];
#pragma unroll
        for (int j = 0; j < 4; ++j) {
          int row = rbase + mi * 16 + j;
          size_t idx = (size_t)row * 1024 + col;
          Cf[idx] = resid[idx] + sc * acc[mi][nf][j];
        }
      }
  } else {
    const int which = colbase >> 10;
    const int hh = (colbase >> 6) & 15;
    if (which == 2) {
#pragma unroll
      for (int mi = 0; mi < 4; ++mi)
#pragma unroll
        for (int j = 0; j < 4; ++j) {
          int row = rbase + mi * 16 + j;
          int t = row & (T_S - 1), nn = row >> 12;
          size_t ob = ((size_t)(nn * NH_ + hh) * T_S + t) * 64;
#pragma unroll
          for (int nf = 0; nf < 4; ++nf)
            v_out[ob + nf * 16 + lrow] = f2bf(acc[mi][nf][j]);
        }
    } else {
      unsigned short* dst = which ? k_out : q_out;
#pragma unroll
      for (int mi = 0; mi < 4; ++mi)
#pragma unroll
        for (int j = 0; j < 4; ++j) {
          int row = rbase + mi * 16 + j;
          int t = row & (T_S - 1), nn = row >> 12;
          float ss = 0.0f;
#pragma unroll
          for (int nf = 0; nf < 4; ++nf) ss += acc[mi][nf][j] * acc[mi][nf][j];
          ss += __shfl_xor(ss, 1, 64);
          ss += __shfl_xor(ss, 2, 64);
          ss += __shfl_xor(ss, 4, 64);
          ss += __shfl_xor(ss, 8, 64);
          float sc = rsqrtf(ss * (1.0f / 64.0f) + EPSF);
          size_t ob = ((size_t)(nn * NH_ + hh) * T_S + t) * 64;
#pragma unroll
          for (int nf = 0; nf < 2; ++nf) {
            int dd = nf * 16 + lrow;
            float cs = cosT[t * 32 + dd], sn = sinT[t * 32 + dd];
            float z1 = acc[mi][nf][j] * sc, z2 = acc[mi][nf + 2][j] * sc;
            dst[ob + dd] = f2bf(z1 * cs + z2 * sn);
            dst[ob + dd + 32] = f2bf(z2 * cs - z1 * sn);
          }
        }
    }
  }
}

// ---------------- chunked sliding-window attention (windowed) ----------------
__global__ __launch_bounds__(256) void k_attn(const unsigned short* __restrict__ qh,
                                              const unsigned short* __restrict__ kh,
                                              const unsigned short* __restrict__ vh,
                                              unsigned short* __restrict__ ao) {
  extern __shared__ __align__(16) char lds[];
  unsigned short* Vt = (unsigned short*)lds;                    // [64][264]
  unsigned short* Pb = (unsigned short*)(lds + 64 * 264 * 2);   // 4 x [32][72]
  const int b = blockIdx.x;
  const int c = b & 31, nh = b >> 5;
  const int tid = threadIdx.x, lane = tid & 63, w = tid >> 6;
  const int lrow = lane & 15, g = lane >> 4, lk8 = g * 8;
  const size_t hb = (size_t)nh * T_S * 64;
  const unsigned short* qg = qh + hb + (size_t)c * 128 * 64;
  const unsigned short* kg = kh + hb + ((ptrdiff_t)c * 128 - 128) * 64;
  const unsigned short* vg = vh + hb + ((ptrdiff_t)c * 128 - 128) * 64;

  // stage V transposed via register 8x8 transpose, b128 writes
  {
    const int m_idx = (tid & 7) | ((tid >> 6) << 3);
    const int m0v = m_idx * 8;
    const int d0 = ((tid >> 3) & 7) * 8;
    short8 vv[8];
#pragma unroll
    for (int i = 0; i < 8; ++i) {
      short8 z = {0, 0, 0, 0, 0, 0, 0, 0};
      if (!(c == 0 && m0v < 128)) z = *(const short8*)(vg + (size_t)(m0v + i) * 64 + d0);
      vv[i] = z;
    }
#pragma unroll
    for (int jj = 0; jj < 8; ++jj) {
      short8 wv;
#pragma unroll
      for (int i = 0; i < 8; ++i) wv[i] = vv[i][jj];
      *(short8*)(Vt + (size_t)(d0 + jj) * 264 + m0v) = wv;
    }
  }

  // Q fragments
  bf16x8 qf[2][2];
#pragma unroll
  for (int mi = 0; mi < 2; ++mi)
#pragma unroll
    for (int ks = 0; ks < 2; ++ks)
      qf[mi][ks] =
          *(const bf16x8*)(qg + (size_t)(w * 32 + mi * 16 + lrow) * 64 + ks * 32 + lk8);

  // S = Q K^T over the wave's 10-tile window
  const int nlo = 2 * w;
  f32x4 s[2][10] = {};
#pragma unroll
  for (int u = 0; u < 10; ++u) {
    const int ni = nlo + u;
    if (c == 0 && ni < 8) continue;
    bf16x8 kf0 = *(const bf16x8*)(kg + (size_t)(ni * 16 + lrow) * 64 + lk8);
    bf16x8 kf1 = *(const bf16x8*)(kg + (size_t)(ni * 16 + lrow) * 64 + 32 + lk8);
#pragma unroll
    for (int mi = 0; mi < 2; ++mi) {
      s[mi][u] = mfma16(qf[mi][0], kf0, s[mi][u]);
      s[mi][u] = mfma16(qf[mi][1], kf1, s[mi][u]);
    }
  }

  // mask + scale + row softmax (deferred normalization)
  float invs[2][4];
#pragma unroll
  for (int mi = 0; mi < 2; ++mi) {
#pragma unroll
    for (int j = 0; j < 4; ++j) {
      int jq = w * 32 + mi * 16 + g * 4 + j;
      float mx = -1e30f;
#pragma unroll
      for (int u = 0; u < 10; ++u) {
        int m = (nlo + u) * 16 + lrow;
        bool ok = (m > jq) && (m <= 128 + jq) && (c > 0 || m >= 128);
        float val = ok ? s[mi][u][j] * 0.125f : -1e30f;
        s[mi][u][j] = val;
        mx = fmaxf(mx, val);
      }
#pragma unroll
      for (int d2 = 1; d2 < 16; d2 <<= 1) mx = fmaxf(mx, __shfl_xor(mx, d2, 64));
      float sum = 0.0f;
#pragma unroll
      for (int u = 0; u < 10; ++u) {
        float p = __expf(s[mi][u][j] - mx);
        s[mi][u][j] = p;
        sum += p;
      }
#pragma unroll
      for (int d2 = 1; d2 < 16; d2 <<= 1) sum += __shfl_xor(sum, d2, 64);
      invs[mi][j] = 1.0f / sum;
    }
  }

  __syncthreads();  // Vt staged before PV reads

  // PV over 3 quarters; P staged per-wave in LDS (stride 72), unnormalized
  f32x4 oacc[2][4] = {};
  unsigned short* Pw = Pb + w * (32 * 72);
  const int qlo = w >> 1;
#pragma unroll
  for (int qq = 0; qq < 3; ++qq) {
#pragma unroll
    for (int mi = 0; mi < 2; ++mi)
#pragma unroll
      for (int ni4 = 0; ni4 < 4; ++ni4)
#pragma unroll
        for (int j = 0; j < 4; ++j) {
          int r = mi * 16 + g * 4 + j;
          float val;
          if ((w & 1) == 0) {
            int u = qq * 4 + ni4;
            val = (u < 10) ? s[mi][u < 10 ? u : 0][j] : 0.0f;
          } else {
            int u = qq * 4 + ni4 - 2;
            val = (u >= 0 && u < 10) ? s[mi][(u >= 0 && u < 10) ? u : 0][j] : 0.0f;
          }
          Pw[r * 72 + ni4 * 16 + lrow] = f2bf(val);
        }
    const int qi = qlo + qq;
#pragma unroll
    for (int ks = 0; ks < 2; ++ks) {
      bf16x8 pf[2], vf[4];
#pragma unroll
      for (int mi = 0; mi < 2; ++mi)
        pf[mi] = *(const bf16x8*)&Pw[(mi * 16 + lrow) * 72 + ks * 32 + lk8];
#pragma unroll
      for (int nj = 0; nj < 4; ++nj)
        vf[nj] = *(const bf16x8*)&Vt[(nj * 16 + lrow) * 264 + qi * 64 + ks * 32 + lk8];
#pragma unroll
      for (int mi = 0; mi < 2; ++mi)
#pragma unroll
        for (int nj = 0; nj < 4; ++nj)
          oacc[mi][nj] = mfma16(pf[mi], vf[nj], oacc[mi][nj]);
    }
  }

  const int t0 = c * 128 + w * 32;
  const int n_ = nh >> 4, h_ = nh & 15;
#pragma unroll
  for (int mi = 0; mi < 2; ++mi)
#pragma unroll
    for (int nj = 0; nj < 4; ++nj)
#pragma unroll
      for (int j = 0; j < 4; ++j) {
        int t = t0 + mi * 16 + g * 4 + j;
        int dcol = nj * 16 + lrow;
        ao[((size_t)n_ * T_S + t) * D_M + h_ * 64 + dcol] =
            f2bf(oacc[mi][nj][j] * invs[mi][j]);
      }
}

extern "C" void kernel_launch(void* const* d_in, const int* in_sizes, int n_in,
                              void* d_out, int out_size, void* d_ws, size_t ws_size,
                              hipStream_t stream) {
  const float* x = (const float*)d_in[0];      // [2,4096,1024]
  const float* qkvw = (const float*)d_in[1];   // [3,1024,1024]
  const float* ow = (const float*)d_in[2];     // [1024,1024]
  const float* osc = (const float*)d_in[3];    // [1024]
  float* out = (float*)d_out;

  char* ws = (char*)d_ws;
  unsigned short* xn = (unsigned short*)(ws + 0);
  unsigned short* qkvwb = (unsigned short*)(ws + 16777216);
  unsigned short* owb = (unsigned short*)(ws + 23068672);
  unsigned short* qhb = (unsigned short*)(ws + 25165824);
  unsigned short* khb = (unsigned short*)(ws + 41943040);
  unsigned short* vhb = (unsigned short*)(ws + 58720256);
  unsigned short* aob = (unsigned short*)(ws + 75497472);
  float* cosT = (float*)(ws + 92274688);
  float* sinT = (float*)(ws + 92798976);

  k_rope_tab<<<512, 256, 0, stream>>>(cosT, sinT);
  k_f32_to_bf16<<<3072, 256, 0, stream>>>(qkvw, qkvwb);
  k_f32_to_bf16<<<1024, 256, 0, stream>>>(ow, owb);
  k_rmsnorm_cast<<<8192, 256, 0, stream>>>(x, xn);
  // QKV: grid 64(M) x 12(N) = 768 blocks = 3 exact rounds, XCD-swizzled
  k_gemm2p<0><<<768, 512, 98304, stream>>>(xn, qkvwb, qhb, khb, vhb, nullptr,
                                           nullptr, nullptr, cosT, sinT, 96);
  k_attn<<<1024, 256, 52224, stream>>>(qhb, khb, vhb, aob);
  // O-proj: grid 64(M) x 4(N) = 256 blocks = 1 exact round
  k_gemm2p<1><<<256, 512, 98304, stream>>>(aob, owb, nullptr, nullptr, nullptr, out,
                                           x, osc, nullptr, nullptr, 32);
}

// Round 7
// 150.677 us; speedup vs baseline: 1.0064x; 1.0025x over previous
//
#include <hip/hip_runtime.h>
#include <hip/hip_bf16.h>
#include <stdint.h>
#include <stddef.h>

#define T_S 4096
#define D_M 1024
#define NH_ 16
#define EPSF 1.1920929e-07f

typedef float f32x4 __attribute__((ext_vector_type(4)));
typedef __bf16 bf16x8 __attribute__((ext_vector_type(8)));
typedef short short8 __attribute__((ext_vector_type(8)));
typedef unsigned short ushort4v __attribute__((ext_vector_type(4)));

static __device__ __forceinline__ unsigned short f2bf(float f) {
  unsigned int u = __builtin_bit_cast(unsigned int, f);
  unsigned int r = (u + 0x7fffu + ((u >> 16) & 1u)) >> 16;
  return (unsigned short)r;
}

#define GLDS16(gp, lp) __builtin_amdgcn_global_load_lds( \
    (__attribute__((address_space(1))) void*)(gp),       \
    (__attribute__((address_space(3))) void*)(lp), 16, 0, 0)

static __device__ __forceinline__ f32x4 mfma16(bf16x8 a, bf16x8 b, f32x4 c) {
  return __builtin_amdgcn_mfma_f32_16x16x32_bf16(a, b, c, 0, 0, 0);
}

// ---------------- RoPE cos/sin table: [T][32] ----------------
__global__ __launch_bounds__(256) void k_rope_tab(float* __restrict__ cosT,
                                                  float* __restrict__ sinT) {
  int i = blockIdx.x * 256 + threadIdx.x;  // t*32 + f
  int t = i >> 5, f = i & 31;
  float fr = (f < 16) ? powf(1e-4f, (float)f * (1.0f / 15.0f)) : 0.0f;
  float th = (float)t * fr;
  cosT[i] = cosf(th);
  sinT[i] = sinf(th);
}

// ---------------- f32 -> bf16 ----------------
__global__ __launch_bounds__(256) void k_f32_to_bf16(const float* __restrict__ src,
                                                     unsigned short* __restrict__ dst) {
  int i = blockIdx.x * 256 + threadIdx.x;
  float4 v = ((const float4*)src)[i];
  ushort4v o;
  o.x = f2bf(v.x); o.y = f2bf(v.y); o.z = f2bf(v.z); o.w = f2bf(v.w);
  ((ushort4v*)dst)[i] = o;
}

// ---------------- RMSNorm over D=1024 + cast ----------------
__global__ __launch_bounds__(256) void k_rmsnorm_cast(const float* __restrict__ x,
                                                      unsigned short* __restrict__ xn) {
  const int row = blockIdx.x;
  const int tid = threadIdx.x;
  float4 v = ((const float4*)(x + (size_t)row * D_M))[tid];
  float ss = v.x * v.x + v.y * v.y + v.z * v.z + v.w * v.w;
#pragma unroll
  for (int d = 1; d < 64; d <<= 1) ss += __shfl_xor(ss, d, 64);
  __shared__ float red[4];
  if ((tid & 63) == 0) red[tid >> 6] = ss;
  __syncthreads();
  float sc = rsqrtf((red[0] + red[1] + red[2] + red[3]) * (1.0f / D_M) + EPSF);
  ushort4v o;
  o.x = f2bf(v.x * sc); o.y = f2bf(v.y * sc); o.z = f2bf(v.z * sc); o.w = f2bf(v.w * sc);
  ((ushort4v*)(xn + (size_t)row * D_M))[tid] = o;
}

// ---------------- bf16 GEMM, C = A @ B^T, tri-buffer deep pipeline ----------------
// BM=128, BN=256, BK=64, K=1024 (NT=16). 8 waves (2M x 4N), wave tile 64x64.
// 3 LDS buffers x 48KB = 144KB (1 block/CU). Stage tile T+2 at top of tile T
// (lead ~= 2 tile-times >> HBM latency). Per K-tile: 6 GLDS/thread, 16 ds_read,
// 32 MFMA, ONE vmcnt(6)+barrier.
// Ledger:
//  - stage(T+2) clobbers buf[(T-1)%3]; its last reads completed before the
//    T-1 -> T boundary barrier (read data consumed at MFMA issue under lgkmcnt);
//    stage issued after that barrier => WAR safe.
//  - at end of tile T, outstanding <= 12 (T+1's 6 + T+2's 6); vmcnt(6) forces
//    T+1's loads landed; barrier makes that block-wide => reads of T+1 safe.
//  - tail: no stage for T+2>=16, wait vmcnt(0) before reading T+1=15.
// LDS XOR swizzle both sides (R6-measured 0 conflicts).
// EPI 0: fused per-head RMSNorm+RoPE scatter -> q/k/v head-major [n,h,t,d]
// EPI 1: Cf = resid + scale[col]*acc (f32)
template <int EPI>
__global__ __launch_bounds__(512, 2) void k_gemm3b(
    const unsigned short* __restrict__ A, const unsigned short* __restrict__ B,
    unsigned short* __restrict__ q_out, unsigned short* __restrict__ k_out,
    unsigned short* __restrict__ v_out, float* __restrict__ Cf,
    const float* __restrict__ resid, const float* __restrict__ scale,
    const float* __restrict__ cosT, const float* __restrict__ sinT,
    int cpx) {
  extern __shared__ __align__(16) char lds[];  // 3 x 49152
  const int tid = threadIdx.x;
  const int lane = tid & 63, w = tid >> 6;
  const int lrow = lane & 15, g4 = lane >> 4;
  const int wm = w >> 2, wn = w & 3;
  const int id = (blockIdx.x & 7) * cpx + (blockIdx.x >> 3);
  const int m0 = (id & 63) * 128, n0 = (id >> 6) * 256;

  // stage a full K-tile t into buffer at byte base bb (6 GLDS/thread)
  auto stage = [&](int t, int bb) {
    const int sgA = ((tid & 3) ^ ((tid >> 3) & 3)) << 3;
    const unsigned short* sa = A + (size_t)(m0 + (tid >> 2)) * 1024 + t * 64 + sgA;
#pragma unroll
    for (int kh = 0; kh < 2; ++kh)
      GLDS16(sa + kh * 32, lds + bb + kh * 8192 + tid * 16);
#pragma unroll
    for (int it = 0; it < 2; ++it) {
      int ci = it * 512 + tid;
      const int sg = ((ci & 3) ^ ((ci >> 3) & 3)) << 3;
      const unsigned short* sb = B + (size_t)(n0 + (ci >> 2)) * 1024 + t * 64 + sg;
#pragma unroll
      for (int kh = 0; kh < 2; ++kh)
        GLDS16(sb + kh * 32, lds + bb + 16384 + kh * 16384 + ci * 16);
    }
  };

  int a_off[2][4], b_off[2][4];
#pragma unroll
  for (int kh = 0; kh < 2; ++kh) {
#pragma unroll
    for (int i = 0; i < 4; ++i) {
      int ar = wm * 64 + i * 16 + lrow;
      a_off[kh][i] = kh * 8192 + ar * 64 + ((g4 ^ ((ar >> 1) & 3)) << 4);
      int br = wn * 64 + i * 16 + lrow;
      b_off[kh][i] = 16384 + kh * 16384 + br * 64 + ((g4 ^ ((br >> 1) & 3)) << 4);
    }
  }

  f32x4 acc[4][4] = {};

  // prologue: stage T0 -> buf0, T1 -> buf1; wait T0 landed
  stage(0, 0);
  stage(1, 49152);
  asm volatile("s_waitcnt vmcnt(6)" ::: "memory");
  __builtin_amdgcn_s_barrier();
  asm volatile("" ::: "memory");

  int cb = 0, sb = 98304;
  for (int T = 0; T < 16; ++T) {
    if (T < 14) stage(T + 2, sb);
    const char* cp = lds + cb;
    bf16x8 aF[2][4], bF[2][4];
#pragma unroll
    for (int kh = 0; kh < 2; ++kh) {
#pragma unroll
      for (int i = 0; i < 4; ++i) aF[kh][i] = *(const bf16x8*)(cp + a_off[kh][i]);
#pragma unroll
      for (int i = 0; i < 4; ++i) bF[kh][i] = *(const bf16x8*)(cp + b_off[kh][i]);
    }
    __builtin_amdgcn_s_setprio(1);
#pragma unroll
    for (int kh = 0; kh < 2; ++kh)
#pragma unroll
      for (int mi = 0; mi < 4; ++mi)
#pragma unroll
        for (int ni = 0; ni < 4; ++ni)
          acc[mi][ni] = mfma16(aF[kh][mi], bF[kh][ni], acc[mi][ni]);
    __builtin_amdgcn_s_setprio(0);
    if (T < 14)
      asm volatile("s_waitcnt vmcnt(6)" ::: "memory");
    else
      asm volatile("s_waitcnt vmcnt(0)" ::: "memory");
    __builtin_amdgcn_s_barrier();
    asm volatile("" ::: "memory");
    cb += 49152; if (cb == 147456) cb = 0;
    sb += 49152; if (sb == 147456) sb = 0;
  }

  const int rbase = m0 + wm * 64 + g4 * 4;  // + mi*16 + j
  const int colbase = n0 + wn * 64;         // wave covers exactly one head

  if (EPI == 1) {
#pragma unroll
    for (int mi = 0; mi < 4; ++mi)
#pragma unroll
      for (int nf = 0; nf < 4; ++nf) {
        int col = colbase + nf * 16 + lrow;
        float sc = scale[col];
#pragma unroll
        for (int j = 0; j < 4; ++j) {
          int row = rbase + mi * 16 + j;
          size_t idx = (size_t)row * 1024 + col;
          Cf[idx] = resid[idx] + sc * acc[mi][nf][j];
        }
      }
  } else {
    const int which = colbase >> 10;
    const int hh = (colbase >> 6) & 15;
    if (which == 2) {
#pragma unroll
      for (int mi = 0; mi < 4; ++mi)
#pragma unroll
        for (int j = 0; j < 4; ++j) {
          int row = rbase + mi * 16 + j;
          int t = row & (T_S - 1), nn = row >> 12;
          size_t ob = ((size_t)(nn * NH_ + hh) * T_S + t) * 64;
#pragma unroll
          for (int nf = 0; nf < 4; ++nf)
            v_out[ob + nf * 16 + lrow] = f2bf(acc[mi][nf][j]);
        }
    } else {
      unsigned short* dst = which ? k_out : q_out;
#pragma unroll
      for (int mi = 0; mi < 4; ++mi)
#pragma unroll
        for (int j = 0; j < 4; ++j) {
          int row = rbase + mi * 16 + j;
          int t = row & (T_S - 1), nn = row >> 12;
          float ss = 0.0f;
#pragma unroll
          for (int nf = 0; nf < 4; ++nf) ss += acc[mi][nf][j] * acc[mi][nf][j];
          ss += __shfl_xor(ss, 1, 64);
          ss += __shfl_xor(ss, 2, 64);
          ss += __shfl_xor(ss, 4, 64);
          ss += __shfl_xor(ss, 8, 64);
          float sc = rsqrtf(ss * (1.0f / 64.0f) + EPSF);
          size_t ob = ((size_t)(nn * NH_ + hh) * T_S + t) * 64;
#pragma unroll
          for (int nf = 0; nf < 2; ++nf) {
            int dd = nf * 16 + lrow;
            float cs = cosT[t * 32 + dd], sn = sinT[t * 32 + dd];
            float z1 = acc[mi][nf][j] * sc, z2 = acc[mi][nf + 2][j] * sc;
            dst[ob + dd] = f2bf(z1 * cs + z2 * sn);
            dst[ob + dd + 32] = f2bf(z2 * cs - z1 * sn);
          }
        }
    }
  }
}

// ---------------- chunked sliding-window attention (windowed) ----------------
__global__ __launch_bounds__(256) void k_attn(const unsigned short* __restrict__ qh,
                                              const unsigned short* __restrict__ kh,
                                              const unsigned short* __restrict__ vh,
                                              unsigned short* __restrict__ ao) {
  extern __shared__ __align__(16) char lds[];
  unsigned short* Vt = (unsigned short*)lds;                    // [64][264]
  unsigned short* Pb = (unsigned short*)(lds + 64 * 264 * 2);   // 4 x [32][72]
  const int b = blockIdx.x;
  const int c = b & 31, nh = b >> 5;
  const int tid = threadIdx.x, lane = tid & 63, w = tid >> 6;
  const int lrow = lane & 15, g = lane >> 4, lk8 = g * 8;
  const size_t hb = (size_t)nh * T_S * 64;
  const unsigned short* qg = qh + hb + (size_t)c * 128 * 64;
  const unsigned short* kg = kh + hb + ((ptrdiff_t)c * 128 - 128) * 64;
  const unsigned short* vg = vh + hb + ((ptrdiff_t)c * 128 - 128) * 64;

  // stage V transposed via register 8x8 transpose, b128 writes
  {
    const int m_idx = (tid & 7) | ((tid >> 6) << 3);
    const int m0v = m_idx * 8;
    const int d0 = ((tid >> 3) & 7) * 8;
    short8 vv[8];
#pragma unroll
    for (int i = 0; i < 8; ++i) {
      short8 z = {0, 0, 0, 0, 0, 0, 0, 0};
      if (!(c == 0 && m0v < 128)) z = *(const short8*)(vg + (size_t)(m0v + i) * 64 + d0);
      vv[i] = z;
    }
#pragma unroll
    for (int jj = 0; jj < 8; ++jj) {
      short8 wv;
#pragma unroll
      for (int i = 0; i < 8; ++i) wv[i] = vv[i][jj];
      *(short8*)(Vt + (size_t)(d0 + jj) * 264 + m0v) = wv;
    }
  }

  // Q fragments
  bf16x8 qf[2][2];
#pragma unroll
  for (int mi = 0; mi < 2; ++mi)
#pragma unroll
    for (int ks = 0; ks < 2; ++ks)
      qf[mi][ks] =
          *(const bf16x8*)(qg + (size_t)(w * 32 + mi * 16 + lrow) * 64 + ks * 32 + lk8);

  // S = Q K^T over the wave's 10-tile window
  const int nlo = 2 * w;
  f32x4 s[2][10] = {};
#pragma unroll
  for (int u = 0; u < 10; ++u) {
    const int ni = nlo + u;
    if (c == 0 && ni < 8) continue;
    bf16x8 kf0 = *(const bf16x8*)(kg + (size_t)(ni * 16 + lrow) * 64 + lk8);
    bf16x8 kf1 = *(const bf16x8*)(kg + (size_t)(ni * 16 + lrow) * 64 + 32 + lk8);
#pragma unroll
    for (int mi = 0; mi < 2; ++mi) {
      s[mi][u] = mfma16(qf[mi][0], kf0, s[mi][u]);
      s[mi][u] = mfma16(qf[mi][1], kf1, s[mi][u]);
    }
  }

  // mask + scale + row softmax (deferred normalization)
  float invs[2][4];
#pragma unroll
  for (int mi = 0; mi < 2; ++mi) {
#pragma unroll
    for (int j = 0; j < 4; ++j) {
      int jq = w * 32 + mi * 16 + g * 4 + j;
      float mx = -1e30f;
#pragma unroll
      for (int u = 0; u < 10; ++u) {
        int m = (nlo + u) * 16 + lrow;
        bool ok = (m > jq) && (m <= 128 + jq) && (c > 0 || m >= 128);
        float val = ok ? s[mi][u][j] * 0.125f : -1e30f;
        s[mi][u][j] = val;
        mx = fmaxf(mx, val);
      }
#pragma unroll
      for (int d2 = 1; d2 < 16; d2 <<= 1) mx = fmaxf(mx, __shfl_xor(mx, d2, 64));
      float sum = 0.0f;
#pragma unroll
      for (int u = 0; u < 10; ++u) {
        float p = __expf(s[mi][u][j] - mx);
        s[mi][u][j] = p;
        sum += p;
      }
#pragma unroll
      for (int d2 = 1; d2 < 16; d2 <<= 1) sum += __shfl_xor(sum, d2, 64);
      invs[mi][j] = 1.0f / sum;
    }
  }

  __syncthreads();  // Vt staged before PV reads

  // PV over 3 quarters; P staged per-wave in LDS (stride 72), unnormalized
  f32x4 oacc[2][4] = {};
  unsigned short* Pw = Pb + w * (32 * 72);
  const int qlo = w >> 1;
#pragma unroll
  for (int qq = 0; qq < 3; ++qq) {
#pragma unroll
    for (int mi = 0; mi < 2; ++mi)
#pragma unroll
      for (int ni4 = 0; ni4 < 4; ++ni4)
#pragma unroll
        for (int j = 0; j < 4; ++j) {
          int r = mi * 16 + g * 4 + j;
          float val;
          if ((w & 1) == 0) {
            int u = qq * 4 + ni4;
            val = (u < 10) ? s[mi][u < 10 ? u : 0][j] : 0.0f;
          } else {
            int u = qq * 4 + ni4 - 2;
            val = (u >= 0 && u < 10) ? s[mi][(u >= 0 && u < 10) ? u : 0][j] : 0.0f;
          }
          Pw[r * 72 + ni4 * 16 + lrow] = f2bf(val);
        }
    const int qi = qlo + qq;
#pragma unroll
    for (int ks = 0; ks < 2; ++ks) {
      bf16x8 pf[2], vf[4];
#pragma unroll
      for (int mi = 0; mi < 2; ++mi)
        pf[mi] = *(const bf16x8*)&Pw[(mi * 16 + lrow) * 72 + ks * 32 + lk8];
#pragma unroll
      for (int nj = 0; nj < 4; ++nj)
        vf[nj] = *(const bf16x8*)&Vt[(nj * 16 + lrow) * 264 + qi * 64 + ks * 32 + lk8];
#pragma unroll
      for (int mi = 0; mi < 2; ++mi)
#pragma unroll
        for (int nj = 0; nj < 4; ++nj)
          oacc[mi][nj] = mfma16(pf[mi], vf[nj], oacc[mi][nj]);
    }
  }

  const int t0 = c * 128 + w * 32;
  const int n_ = nh >> 4, h_ = nh & 15;
#pragma unroll
  for (int mi = 0; mi < 2; ++mi)
#pragma unroll
    for (int nj = 0; nj < 4; ++nj)
#pragma unroll
      for (int j = 0; j < 4; ++j) {
        int t = t0 + mi * 16 + g * 4 + j;
        int dcol = nj * 16 + lrow;
        ao[((size_t)n_ * T_S + t) * D_M + h_ * 64 + dcol] =
            f2bf(oacc[mi][nj][j] * invs[mi][j]);
      }
}

extern "C" void kernel_launch(void* const* d_in, const int* in_sizes, int n_in,
                              void* d_out, int out_size, void* d_ws, size_t ws_size,
                              hipStream_t stream) {
  const float* x = (const float*)d_in[0];      // [2,4096,1024]
  const float* qkvw = (const float*)d_in[1];   // [3,1024,1024]
  const float* ow = (const float*)d_in[2];     // [1024,1024]
  const float* osc = (const float*)d_in[3];    // [1024]
  float* out = (float*)d_out;

  char* ws = (char*)d_ws;
  unsigned short* xn = (unsigned short*)(ws + 0);
  unsigned short* qkvwb = (unsigned short*)(ws + 16777216);
  unsigned short* owb = (unsigned short*)(ws + 23068672);
  unsigned short* qhb = (unsigned short*)(ws + 25165824);
  unsigned short* khb = (unsigned short*)(ws + 41943040);
  unsigned short* vhb = (unsigned short*)(ws + 58720256);
  unsigned short* aob = (unsigned short*)(ws + 75497472);
  float* cosT = (float*)(ws + 92274688);
  float* sinT = (float*)(ws + 92798976);

  k_rope_tab<<<512, 256, 0, stream>>>(cosT, sinT);
  k_f32_to_bf16<<<3072, 256, 0, stream>>>(qkvw, qkvwb);
  k_f32_to_bf16<<<1024, 256, 0, stream>>>(ow, owb);
  k_rmsnorm_cast<<<8192, 256, 0, stream>>>(x, xn);
  // QKV: grid 64(M) x 12(N) = 768 blocks = 3 exact rounds at 1 block/CU
  k_gemm3b<0><<<768, 512, 147456, stream>>>(xn, qkvwb, qhb, khb, vhb, nullptr,
                                            nullptr, nullptr, cosT, sinT, 96);
  k_attn<<<1024, 256, 52224, stream>>>(qhb, khb, vhb, aob);
  // O-proj: grid 64(M) x 4(N) = 256 blocks = 1 exact round
  k_gemm3b<1><<<256, 512, 147456, stream>>>(aob, owb, nullptr, nullptr, nullptr, out,
                                            x, osc, nullptr, nullptr, 32);
}

// Round 8
// 144.533 us; speedup vs baseline: 1.0491x; 1.0425x over previous
//
#include <hip/hip_runtime.h>
#include <hip/hip_bf16.h>
#include <stdint.h>
#include <stddef.h>

#define T_S 4096
#define D_M 1024
#define NH_ 16
#define EPSF 1.1920929e-07f

typedef float f32x4 __attribute__((ext_vector_type(4)));
typedef __bf16 bf16x8 __attribute__((ext_vector_type(8)));
typedef short short8 __attribute__((ext_vector_type(8)));
typedef unsigned short ushort4v __attribute__((ext_vector_type(4)));

static __device__ __forceinline__ unsigned short f2bf(float f) {
  return __builtin_bit_cast(unsigned short, (__bf16)f);  // native RNE cvt
}

#define GLDS16(gp, lp) __builtin_amdgcn_global_load_lds( \
    (__attribute__((address_space(1))) void*)(gp),       \
    (__attribute__((address_space(3))) void*)(lp), 16, 0, 0)

static __device__ __forceinline__ f32x4 mfma16(bf16x8 a, bf16x8 b, f32x4 c) {
  return __builtin_amdgcn_mfma_f32_16x16x32_bf16(a, b, c, 0, 0, 0);
}

// ---------------- RoPE cos/sin table: [T][32] ----------------
__global__ __launch_bounds__(256) void k_rope_tab(float* __restrict__ cosT,
                                                  float* __restrict__ sinT) {
  int i = blockIdx.x * 256 + threadIdx.x;  // t*32 + f
  int t = i >> 5, f = i & 31;
  float fr = (f < 16) ? powf(1e-4f, (float)f * (1.0f / 15.0f)) : 0.0f;
  float th = (float)t * fr;
  cosT[i] = cosf(th);
  sinT[i] = sinf(th);
}

// ---------------- f32 -> bf16 ----------------
__global__ __launch_bounds__(256) void k_f32_to_bf16(const float* __restrict__ src,
                                                     unsigned short* __restrict__ dst) {
  int i = blockIdx.x * 256 + threadIdx.x;
  float4 v = ((const float4*)src)[i];
  ushort4v o;
  o.x = f2bf(v.x); o.y = f2bf(v.y); o.z = f2bf(v.z); o.w = f2bf(v.w);
  ((ushort4v*)dst)[i] = o;
}

// ---------------- RMSNorm over D=1024 + cast ----------------
__global__ __launch_bounds__(256) void k_rmsnorm_cast(const float* __restrict__ x,
                                                      unsigned short* __restrict__ xn) {
  const int row = blockIdx.x;
  const int tid = threadIdx.x;
  float4 v = ((const float4*)(x + (size_t)row * D_M))[tid];
  float ss = v.x * v.x + v.y * v.y + v.z * v.z + v.w * v.w;
#pragma unroll
  for (int d = 1; d < 64; d <<= 1) ss += __shfl_xor(ss, d, 64);
  __shared__ float red[4];
  if ((tid & 63) == 0) red[tid >> 6] = ss;
  __syncthreads();
  float sc = rsqrtf((red[0] + red[1] + red[2] + red[3]) * (1.0f / D_M) + EPSF);
  ushort4v o;
  o.x = f2bf(v.x * sc); o.y = f2bf(v.y * sc); o.z = f2bf(v.z * sc); o.w = f2bf(v.w * sc);
  ((ushort4v*)(xn + (size_t)row * D_M))[tid] = o;
}

// ---------------- bf16 GEMM, C = A @ B^T, 3-stage pipeline (R2/R4-proven) ----------------
// BM=256, BN=128, BK=32; 8 waves (4M x 2N), wave tile 64x64; 3 LDS buffers.
// EPI 0: fused per-head RMSNorm+RoPE scatter -> q/k/v head-major bf16 [n,h,t,d]
// EPI 1: Cf = resid + scale[col]*acc (f32)
template <int EPI>
__global__ __launch_bounds__(512) void k_gemm256(
    const unsigned short* __restrict__ A, const unsigned short* __restrict__ B,
    unsigned short* __restrict__ q_out, unsigned short* __restrict__ k_out,
    unsigned short* __restrict__ v_out, float* __restrict__ Cf,
    const float* __restrict__ resid, const float* __restrict__ scale,
    const float* __restrict__ cosT, const float* __restrict__ sinT,
    int M, int Ncols, int K) {
  extern __shared__ __align__(16) char lds[];  // 3 x (16384 A + 8192 B) = 73728 B
  const int tid = threadIdx.x;
  const int lane = tid & 63, w = tid >> 6;
  const int lrow = lane & 15, g = lane >> 4;
  const int wm = w >> 1, wn = w & 1;
  const int m0 = blockIdx.y * 256, n0 = blockIdx.x * 128;
  const int NT = K >> 5;

  const int srcgrp = (((tid & 3) ^ ((tid >> 3) & 3)) << 3);
  const size_t aoff0 = (size_t)(m0 + (tid >> 2)) * K + srcgrp;
  const size_t aoff1 = aoff0 + (size_t)128 * K;
  const size_t boff = (size_t)(n0 + (tid >> 2)) * K + srcgrp;
  const int wbase = w * 1024;

  int abyte[4], bbyte[4];
#pragma unroll
  for (int i = 0; i < 4; ++i) {
    int ar = wm * 64 + i * 16 + lrow;
    abyte[i] = ar * 64 + ((g ^ ((ar >> 1) & 3)) << 4);
    int br = wn * 64 + i * 16 + lrow;
    bbyte[i] = 16384 + br * 64 + ((g ^ ((br >> 1) & 3)) << 4);
  }

  f32x4 acc[4][4] = {};

#pragma unroll
  for (int t = 0; t < 2; ++t) {
    char* sp = lds + t * 24576;
    GLDS16(A + aoff0 + t * 32, sp + wbase);
    GLDS16(A + aoff1 + t * 32, sp + 8192 + wbase);
    GLDS16(B + boff + t * 32, sp + 16384 + wbase);
  }
  asm volatile("s_waitcnt vmcnt(3)" ::: "memory");
  __builtin_amdgcn_s_barrier();
  asm volatile("" ::: "memory");

  int cb = 0, sb = 49152;
  for (int t = 0; t < NT; ++t) {
    if (t + 2 < NT) {
      const int kt2 = (t + 2) << 5;
      char* sp = lds + sb;
      GLDS16(A + aoff0 + kt2, sp + wbase);
      GLDS16(A + aoff1 + kt2, sp + 8192 + wbase);
      GLDS16(B + boff + kt2, sp + 16384 + wbase);
    }
    const char* cp = lds + cb;
    bf16x8 aF[4], bF[4];
#pragma unroll
    for (int i = 0; i < 4; ++i) aF[i] = *(const bf16x8*)(cp + abyte[i]);
#pragma unroll
    for (int i = 0; i < 4; ++i) bF[i] = *(const bf16x8*)(cp + bbyte[i]);
    __builtin_amdgcn_s_setprio(1);
#pragma unroll
    for (int mi = 0; mi < 4; ++mi)
#pragma unroll
      for (int ni = 0; ni < 4; ++ni)
        acc[mi][ni] = mfma16(aF[mi], bF[ni], acc[mi][ni]);
    __builtin_amdgcn_s_setprio(0);
    if (t + 2 < NT)
      asm volatile("s_waitcnt vmcnt(3)" ::: "memory");
    else
      asm volatile("s_waitcnt vmcnt(0)" ::: "memory");
    __builtin_amdgcn_s_barrier();
    asm volatile("" ::: "memory");
    cb += 24576; if (cb == 73728) cb = 0;
    sb += 24576; if (sb == 73728) sb = 0;
  }

  const int rbase = m0 + wm * 64 + g * 4;  // + mi*16 + j
  const int colbase = n0 + wn * 64;        // wave covers exactly one head

  if (EPI == 1) {
#pragma unroll
    for (int mi = 0; mi < 4; ++mi)
#pragma unroll
      for (int nf = 0; nf < 4; ++nf) {
        int col = colbase + nf * 16 + lrow;
        float sc = scale[col];
#pragma unroll
        for (int j = 0; j < 4; ++j) {
          int row = rbase + mi * 16 + j;
          size_t idx = (size_t)row * Ncols + col;
          Cf[idx] = resid[idx] + sc * acc[mi][nf][j];
        }
      }
  } else {
    const int which = colbase >> 10;
    const int hh = (colbase >> 6) & 15;
    if (which == 2) {
#pragma unroll
      for (int mi = 0; mi < 4; ++mi)
#pragma unroll
        for (int j = 0; j < 4; ++j) {
          int row = rbase + mi * 16 + j;
          int t = row & (T_S - 1), nn = row >> 12;
          size_t ob = ((size_t)(nn * NH_ + hh) * T_S + t) * 64;
#pragma unroll
          for (int nf = 0; nf < 4; ++nf)
            v_out[ob + nf * 16 + lrow] = f2bf(acc[mi][nf][j]);
        }
    } else {
      unsigned short* dst = which ? k_out : q_out;
#pragma unroll
      for (int mi = 0; mi < 4; ++mi)
#pragma unroll
        for (int j = 0; j < 4; ++j) {
          int row = rbase + mi * 16 + j;
          int t = row & (T_S - 1), nn = row >> 12;
          float ss = 0.0f;
#pragma unroll
          for (int nf = 0; nf < 4; ++nf) ss += acc[mi][nf][j] * acc[mi][nf][j];
          ss += __shfl_xor(ss, 1, 64);
          ss += __shfl_xor(ss, 2, 64);
          ss += __shfl_xor(ss, 4, 64);
          ss += __shfl_xor(ss, 8, 64);
          float sc = rsqrtf(ss * (1.0f / 64.0f) + EPSF);
          size_t ob = ((size_t)(nn * NH_ + hh) * T_S + t) * 64;
#pragma unroll
          for (int nf = 0; nf < 2; ++nf) {
            int dd = nf * 16 + lrow;
            float cs = cosT[t * 32 + dd], sn = sinT[t * 32 + dd];
            float z1 = acc[mi][nf][j] * sc, z2 = acc[mi][nf + 2][j] * sc;
            dst[ob + dd] = f2bf(z1 * cs + z2 * sn);
            dst[ob + dd + 32] = f2bf(z2 * cs - z1 * sn);
          }
        }
    }
  }
}

// ---------------- chunked sliding-window attention (windowed, T14 async-V) ----------------
// block = (n,h,c): 4 waves x 32 q-rows; wave w needs only key tiles
// ni in [2w, 2w+9]; PV over 3 quarters qlo..qlo+2.
// T14: V global loads issued at top; transpose-write to LDS deferred until
// after softmax so HBM latency hides under QK^T+softmax.
__global__ __launch_bounds__(256, 2) void k_attn(const unsigned short* __restrict__ qh,
                                                 const unsigned short* __restrict__ kh,
                                                 const unsigned short* __restrict__ vh,
                                                 unsigned short* __restrict__ ao) {
  extern __shared__ __align__(16) char lds[];
  unsigned short* Vt = (unsigned short*)lds;                    // [64][264]
  unsigned short* Pb = (unsigned short*)(lds + 64 * 264 * 2);   // 4 x [32][72]
  const int b = blockIdx.x;
  const int c = b & 31, nh = b >> 5;
  const int tid = threadIdx.x, lane = tid & 63, w = tid >> 6;
  const int lrow = lane & 15, g = lane >> 4, lk8 = g * 8;
  const size_t hb = (size_t)nh * T_S * 64;
  const unsigned short* qg = qh + hb + (size_t)c * 128 * 64;
  const unsigned short* kg = kh + hb + ((ptrdiff_t)c * 128 - 128) * 64;
  const unsigned short* vg = vh + hb + ((ptrdiff_t)c * 128 - 128) * 64;

  // ---- issue V loads early (consumed after softmax) ----
  const int m_idx = (tid & 7) | ((tid >> 6) << 3);
  const int m0v = m_idx * 8;
  const int d0 = ((tid >> 3) & 7) * 8;
  short8 vv[8];
#pragma unroll
  for (int i = 0; i < 8; ++i) {
    short8 z = {0, 0, 0, 0, 0, 0, 0, 0};
    if (!(c == 0 && m0v < 128)) z = *(const short8*)(vg + (size_t)(m0v + i) * 64 + d0);
    vv[i] = z;
  }

  // Q fragments
  bf16x8 qf[2][2];
#pragma unroll
  for (int mi = 0; mi < 2; ++mi)
#pragma unroll
    for (int ks = 0; ks < 2; ++ks)
      qf[mi][ks] =
          *(const bf16x8*)(qg + (size_t)(w * 32 + mi * 16 + lrow) * 64 + ks * 32 + lk8);

  // S = Q K^T over the wave's 10-tile window
  const int nlo = 2 * w;
  f32x4 s[2][10] = {};
#pragma unroll
  for (int u = 0; u < 10; ++u) {
    const int ni = nlo + u;
    if (c == 0 && ni < 8) continue;
    bf16x8 kf0 = *(const bf16x8*)(kg + (size_t)(ni * 16 + lrow) * 64 + lk8);
    bf16x8 kf1 = *(const bf16x8*)(kg + (size_t)(ni * 16 + lrow) * 64 + 32 + lk8);
#pragma unroll
    for (int mi = 0; mi < 2; ++mi) {
      s[mi][u] = mfma16(qf[mi][0], kf0, s[mi][u]);
      s[mi][u] = mfma16(qf[mi][1], kf1, s[mi][u]);
    }
  }

  // mask + scale + row softmax (deferred normalization)
  float invs[2][4];
#pragma unroll
  for (int mi = 0; mi < 2; ++mi) {
#pragma unroll
    for (int j = 0; j < 4; ++j) {
      int jq = w * 32 + mi * 16 + g * 4 + j;
      float mx = -1e30f;
#pragma unroll
      for (int u = 0; u < 10; ++u) {
        int m = (nlo + u) * 16 + lrow;
        bool ok = (m > jq) && (m <= 128 + jq) && (c > 0 || m >= 128);
        float val = ok ? s[mi][u][j] * 0.125f : -1e30f;
        s[mi][u][j] = val;
        mx = fmaxf(mx, val);
      }
#pragma unroll
      for (int d2 = 1; d2 < 16; d2 <<= 1) mx = fmaxf(mx, __shfl_xor(mx, d2, 64));
      float sum = 0.0f;
#pragma unroll
      for (int u = 0; u < 10; ++u) {
        float p = __expf(s[mi][u][j] - mx);
        s[mi][u][j] = p;
        sum += p;
      }
#pragma unroll
      for (int d2 = 1; d2 < 16; d2 <<= 1) sum += __shfl_xor(sum, d2, 64);
      invs[mi][j] = 1.0f / sum;
    }
  }

  // ---- now commit V to LDS (transposed), then sync ----
#pragma unroll
  for (int jj = 0; jj < 8; ++jj) {
    short8 wv;
#pragma unroll
    for (int i = 0; i < 8; ++i) wv[i] = vv[i][jj];
    *(short8*)(Vt + (size_t)(d0 + jj) * 264 + m0v) = wv;
  }
  __syncthreads();  // Vt staged before PV reads

  // PV over 3 quarters; P staged per-wave in LDS (stride 72), unnormalized
  f32x4 oacc[2][4] = {};
  unsigned short* Pw = Pb + w * (32 * 72);
  const int qlo = w >> 1;
#pragma unroll
  for (int qq = 0; qq < 3; ++qq) {
#pragma unroll
    for (int mi = 0; mi < 2; ++mi)
#pragma unroll
      for (int ni4 = 0; ni4 < 4; ++ni4)
#pragma unroll
        for (int j = 0; j < 4; ++j) {
          int r = mi * 16 + g * 4 + j;
          float val;
          if ((w & 1) == 0) {
            int u = qq * 4 + ni4;
            val = (u < 10) ? s[mi][u < 10 ? u : 0][j] : 0.0f;
          } else {
            int u = qq * 4 + ni4 - 2;
            val = (u >= 0 && u < 10) ? s[mi][(u >= 0 && u < 10) ? u : 0][j] : 0.0f;
          }
          Pw[r * 72 + ni4 * 16 + lrow] = f2bf(val);
        }
    const int qi = qlo + qq;
#pragma unroll
    for (int ks = 0; ks < 2; ++ks) {
      bf16x8 pf[2], vf[4];
#pragma unroll
      for (int mi = 0; mi < 2; ++mi)
        pf[mi] = *(const bf16x8*)&Pw[(mi * 16 + lrow) * 72 + ks * 32 + lk8];
#pragma unroll
      for (int nj = 0; nj < 4; ++nj)
        vf[nj] = *(const bf16x8*)&Vt[(nj * 16 + lrow) * 264 + qi * 64 + ks * 32 + lk8];
#pragma unroll
      for (int mi = 0; mi < 2; ++mi)
#pragma unroll
        for (int nj = 0; nj < 4; ++nj)
          oacc[mi][nj] = mfma16(pf[mi], vf[nj], oacc[mi][nj]);
    }
  }

  const int t0 = c * 128 + w * 32;
  const int n_ = nh >> 4, h_ = nh & 15;
#pragma unroll
  for (int mi = 0; mi < 2; ++mi)
#pragma unroll
    for (int nj = 0; nj < 4; ++nj)
#pragma unroll
      for (int j = 0; j < 4; ++j) {
        int t = t0 + mi * 16 + g * 4 + j;
        int dcol = nj * 16 + lrow;
        ao[((size_t)n_ * T_S + t) * D_M + h_ * 64 + dcol] =
            f2bf(oacc[mi][nj][j] * invs[mi][j]);
      }
}

extern "C" void kernel_launch(void* const* d_in, const int* in_sizes, int n_in,
                              void* d_out, int out_size, void* d_ws, size_t ws_size,
                              hipStream_t stream) {
  const float* x = (const float*)d_in[0];      // [2,4096,1024]
  const float* qkvw = (const float*)d_in[1];   // [3,1024,1024]
  const float* ow = (const float*)d_in[2];     // [1024,1024]
  const float* osc = (const float*)d_in[3];    // [1024]
  float* out = (float*)d_out;

  char* ws = (char*)d_ws;
  unsigned short* xn = (unsigned short*)(ws + 0);
  unsigned short* qkvwb = (unsigned short*)(ws + 16777216);
  unsigned short* owb = (unsigned short*)(ws + 23068672);
  unsigned short* qhb = (unsigned short*)(ws + 25165824);
  unsigned short* khb = (unsigned short*)(ws + 41943040);
  unsigned short* vhb = (unsigned short*)(ws + 58720256);
  unsigned short* aob = (unsigned short*)(ws + 75497472);
  float* cosT = (float*)(ws + 92274688);
  float* sinT = (float*)(ws + 92798976);

  k_rope_tab<<<512, 256, 0, stream>>>(cosT, sinT);
  k_f32_to_bf16<<<3072, 256, 0, stream>>>(qkvw, qkvwb);
  k_f32_to_bf16<<<1024, 256, 0, stream>>>(ow, owb);
  k_rmsnorm_cast<<<8192, 256, 0, stream>>>(x, xn);
  k_gemm256<0><<<dim3(24, 32), 512, 73728, stream>>>(xn, qkvwb, qhb, khb, vhb, nullptr,
                                                     nullptr, nullptr, cosT, sinT,
                                                     8192, 3072, 1024);
  k_attn<<<1024, 256, 52224, stream>>>(qhb, khb, vhb, aob);
  k_gemm256<1><<<dim3(8, 32), 512, 73728, stream>>>(aob, owb, nullptr, nullptr, nullptr,
                                                    out, x, osc, nullptr, nullptr,
                                                    8192, 1024, 1024);
}